// Round 1
// baseline (4859.439 us; speedup 1.0000x reference)
//
#include <hip/hip_runtime.h>
#include <math.h>

#define D_MODEL 1024
#define HDIM 64

// ---------------- LayerNorm: one block (256 thr) per 1024-wide row ----------
__global__ __launch_bounds__(256) void ln_kernel(
    const float* __restrict__ in, const float* __restrict__ gw,
    const float* __restrict__ bw, float* __restrict__ out) {
  int row = blockIdx.x;
  const float4* rp = (const float4*)(in + (size_t)row * D_MODEL);
  float4 v = rp[threadIdx.x];
  float s = v.x + v.y + v.z + v.w;
  float ss = v.x * v.x + v.y * v.y + v.z * v.z + v.w * v.w;
#pragma unroll
  for (int o = 32; o; o >>= 1) {
    s += __shfl_down(s, o);
    ss += __shfl_down(ss, o);
  }
  __shared__ float red[10];
  int lane = threadIdx.x & 63, wid = threadIdx.x >> 6;
  if (lane == 0) { red[wid] = s; red[4 + wid] = ss; }
  __syncthreads();
  if (threadIdx.x == 0) {
    float ts = red[0] + red[1] + red[2] + red[3];
    float tss = red[4] + red[5] + red[6] + red[7];
    float mean = ts * (1.0f / D_MODEL);
    float var = tss * (1.0f / D_MODEL) - mean * mean;
    red[8] = mean;
    red[9] = rsqrtf(var + 1e-5f);
  }
  __syncthreads();
  float mean = red[8], rstd = red[9];
  float4 g = ((const float4*)gw)[threadIdx.x];
  float4 b = ((const float4*)bw)[threadIdx.x];
  float4 o;
  o.x = (v.x - mean) * rstd * g.x + b.x;
  o.y = (v.y - mean) * rstd * g.y + b.y;
  o.z = (v.z - mean) * rstd * g.z + b.z;
  o.w = (v.w - mean) * rstd * g.w + b.w;
  ((float4*)(out + (size_t)row * D_MODEL))[threadIdx.x] = o;
}

// ---------------- fp32 GEMM: C[M,N] = act(A[M,K]@B[K,N]) (+R) ---------------
// 64x64 tile, BK=16, 256 threads, 4x4 per thread. GELU_ACT: exact gelu.
template <int GELU_ACT>
__global__ __launch_bounds__(256) void gemm_kernel(
    const float* __restrict__ A, const float* __restrict__ Bm,
    const float* __restrict__ Rm, float* __restrict__ C, int M, int N, int K) {
  __shared__ float As[16][68];  // transposed: As[k][m]
  __shared__ float Bs[16][68];
  int bn = blockIdx.x, bm = blockIdx.y;
  int tid = threadIdx.x;
  int tx = tid & 15, ty = tid >> 4;
  const float* Ab = A + (size_t)bm * 64 * K;
  const float* Bb = Bm + (size_t)bn * 64;
  float acc[4][4] = {};
  int am = tid >> 2, akq = tid & 3;
  int bk = tid >> 4, bnq = tid & 15;
  for (int k0 = 0; k0 < K; k0 += 16) {
    float4 a = *(const float4*)(Ab + (size_t)am * K + k0 + akq * 4);
    float4 b = *(const float4*)(Bb + (size_t)(k0 + bk) * N + bnq * 4);
    As[akq * 4 + 0][am] = a.x;
    As[akq * 4 + 1][am] = a.y;
    As[akq * 4 + 2][am] = a.z;
    As[akq * 4 + 3][am] = a.w;
    *(float4*)(&Bs[bk][bnq * 4]) = b;
    __syncthreads();
#pragma unroll
    for (int kk = 0; kk < 16; ++kk) {
      float4 av = *(const float4*)(&As[kk][ty * 4]);
      float4 bv = *(const float4*)(&Bs[kk][tx * 4]);
      acc[0][0] += av.x * bv.x; acc[0][1] += av.x * bv.y;
      acc[0][2] += av.x * bv.z; acc[0][3] += av.x * bv.w;
      acc[1][0] += av.y * bv.x; acc[1][1] += av.y * bv.y;
      acc[1][2] += av.y * bv.z; acc[1][3] += av.y * bv.w;
      acc[2][0] += av.z * bv.x; acc[2][1] += av.z * bv.y;
      acc[2][2] += av.z * bv.z; acc[2][3] += av.z * bv.w;
      acc[3][0] += av.w * bv.x; acc[3][1] += av.w * bv.y;
      acc[3][2] += av.w * bv.z; acc[3][3] += av.w * bv.w;
    }
    __syncthreads();
  }
  size_t colBase = (size_t)bn * 64 + tx * 4;
#pragma unroll
  for (int i = 0; i < 4; ++i) {
    size_t row = (size_t)bm * 64 + ty * 4 + i;
    float4 v = make_float4(acc[i][0], acc[i][1], acc[i][2], acc[i][3]);
    if (GELU_ACT) {
      v.x = 0.5f * v.x * (1.0f + erff(v.x * 0.70710678118654752f));
      v.y = 0.5f * v.y * (1.0f + erff(v.y * 0.70710678118654752f));
      v.z = 0.5f * v.z * (1.0f + erff(v.z * 0.70710678118654752f));
      v.w = 0.5f * v.w * (1.0f + erff(v.w * 0.70710678118654752f));
    }
    if (Rm != nullptr) {
      float4 r = *(const float4*)(Rm + row * N + colBase);
      v.x += r.x; v.y += r.y; v.z += r.z; v.w += r.w;
    }
    *(float4*)(C + row * N + colBase) = v;
  }
}

// ---------------- fused flash attention -------------------------------------
// Q/K/V/O in merged (rows, 1024) layout; head h occupies cols h*64..h*64+63.
// Block: 256 thr; 64 q-rows per block; thread t owns row r=t>>2, col group cg=t&3.
template <bool CAUSAL>
__global__ __launch_bounds__(256) void attn_kernel(
    const float* __restrict__ Qm, const float* __restrict__ Km,
    const float* __restrict__ Vm, float* __restrict__ Om, int Tk,
    size_t qStrideB, size_t kStrideB) {
  int qt = blockIdx.x, h = blockIdx.y, bz = blockIdx.z;
  const float* Qb = Qm + (size_t)bz * qStrideB + h * HDIM;
  const float* Kb = Km + (size_t)bz * kStrideB + h * HDIM;
  const float* Vb = Vm + (size_t)bz * kStrideB + h * HDIM;
  float* Ob = Om + (size_t)bz * qStrideB + h * HDIM;

  __shared__ float Qs[64][68];
  __shared__ float Ks[64][68];
  __shared__ float Vs[64][68];
  __shared__ float Ps[64][68];

  int tid = threadIdx.x;
  int r = tid >> 2, cg = tid & 3;
  int lrow = tid >> 2, lq4 = tid & 3;

  {
    const float* src = Qb + (size_t)(qt * 64 + lrow) * D_MODEL;
#pragma unroll
    for (int i = 0; i < 4; ++i)
      *(float4*)(&Qs[lrow][(lq4 + 4 * i) * 4]) =
          *(const float4*)(src + (lq4 + 4 * i) * 4);
  }

  float m_r = -INFINITY, l_r = 0.0f;
  float o[16];
#pragma unroll
  for (int j = 0; j < 16; ++j) o[j] = 0.0f;

  int ktMax = CAUSAL ? qt : (Tk / 64 - 1);
  int qi = qt * 64 + r;
  for (int kt = 0; kt <= ktMax; ++kt) {
    __syncthreads();  // prev iter's P@V done before overwriting K/V/P
    {
      const float* ksrc = Kb + (size_t)(kt * 64 + lrow) * D_MODEL;
      const float* vsrc = Vb + (size_t)(kt * 64 + lrow) * D_MODEL;
#pragma unroll
      for (int i = 0; i < 4; ++i) {
        *(float4*)(&Ks[lrow][(lq4 + 4 * i) * 4]) =
            *(const float4*)(ksrc + (lq4 + 4 * i) * 4);
        *(float4*)(&Vs[lrow][(lq4 + 4 * i) * 4]) =
            *(const float4*)(vsrc + (lq4 + 4 * i) * 4);
      }
    }
    __syncthreads();
    float s[16];
#pragma unroll
    for (int j = 0; j < 16; ++j) s[j] = 0.0f;
#pragma unroll 4
    for (int k4 = 0; k4 < 16; ++k4) {
      float4 qv = *(const float4*)(&Qs[r][k4 * 4]);
#pragma unroll
      for (int j = 0; j < 16; ++j) {
        float4 kv = *(const float4*)(&Ks[cg * 16 + j][k4 * 4]);
        s[j] += qv.x * kv.x + qv.y * kv.y + qv.z * kv.z + qv.w * kv.w;
      }
    }
    float tmax = -INFINITY;
#pragma unroll
    for (int j = 0; j < 16; ++j) {
      float sv = s[j] * 0.125f;
      if (CAUSAL && (kt * 64 + cg * 16 + j) > qi) sv = -INFINITY;
      s[j] = sv;
      tmax = fmaxf(tmax, sv);
    }
    tmax = fmaxf(tmax, __shfl_xor(tmax, 1));
    tmax = fmaxf(tmax, __shfl_xor(tmax, 2));
    float m_new = fmaxf(m_r, tmax);
    float alpha = expf(m_r - m_new);  // m_r=-inf -> 0
    float rowsum = 0.0f;
#pragma unroll
    for (int j = 0; j < 16; ++j) {
      float p = expf(s[j] - m_new);
      s[j] = p;
      rowsum += p;
    }
    rowsum += __shfl_xor(rowsum, 1);
    rowsum += __shfl_xor(rowsum, 2);
    l_r = l_r * alpha + rowsum;
    m_r = m_new;
#pragma unroll
    for (int j = 0; j < 16; ++j) o[j] *= alpha;
#pragma unroll
    for (int j4 = 0; j4 < 4; ++j4)
      *(float4*)(&Ps[r][cg * 16 + j4 * 4]) =
          make_float4(s[j4 * 4], s[j4 * 4 + 1], s[j4 * 4 + 2], s[j4 * 4 + 3]);
    __syncthreads();
#pragma unroll 8
    for (int kk = 0; kk < 64; ++kk) {
      float p = Ps[r][kk];
#pragma unroll
      for (int j4 = 0; j4 < 4; ++j4) {
        float4 vv = *(const float4*)(&Vs[kk][cg * 16 + j4 * 4]);
        o[j4 * 4 + 0] += p * vv.x;
        o[j4 * 4 + 1] += p * vv.y;
        o[j4 * 4 + 2] += p * vv.z;
        o[j4 * 4 + 3] += p * vv.w;
      }
    }
  }
  float inv = 1.0f / l_r;
  float* dst = Ob + (size_t)(qt * 64 + r) * D_MODEL + cg * 16;
#pragma unroll
  for (int j4 = 0; j4 < 4; ++j4)
    *(float4*)(dst + j4 * 4) =
        make_float4(o[j4 * 4] * inv, o[j4 * 4 + 1] * inv, o[j4 * 4 + 2] * inv,
                    o[j4 * 4 + 3] * inv);
}

// ---------------- driver ----------------------------------------------------
extern "C" void kernel_launch(void* const* d_in, const int* in_sizes, int n_in,
                              void* d_out, int out_size, void* d_ws,
                              size_t ws_size, hipStream_t stream) {
  const float* x = (const float*)d_in[0];
  const float* neigh = (const float*)d_in[1];
  const float* sa_ln_g = (const float*)d_in[2];
  const float* sa_ln_b = (const float*)d_in[3];
  const float* sa_wq = (const float*)d_in[4];
  const float* sa_wk = (const float*)d_in[5];
  const float* sa_wv = (const float*)d_in[6];
  const float* sa_wo = (const float*)d_in[7];
  const float* cca_lnq_g = (const float*)d_in[8];
  const float* cca_lnq_b = (const float*)d_in[9];
  const float* cca_lnkv_g = (const float*)d_in[10];
  const float* cca_lnkv_b = (const float*)d_in[11];
  const float* cca_wq = (const float*)d_in[12];
  const float* cca_wk = (const float*)d_in[13];
  const float* cca_wv = (const float*)d_in[14];
  const float* cca_wo = (const float*)d_in[15];
  const float* ffn_ln_g = (const float*)d_in[16];
  const float* ffn_ln_b = (const float*)d_in[17];
  const float* ffn_w1 = (const float*)d_in[18];
  const float* ffn_w2 = (const float*)d_in[19];
  float* out = (float*)d_out;

  // workspace layout (fp32): 5 x 16MB + 3 x 32MB = 176 MB
  float* ws = (float*)d_ws;
  const size_t S16 = (size_t)4096 * 1024;  // 4M floats
  const size_t W8 = (size_t)8192 * 1024;   // 8M floats
  float* S0 = ws;            // ln1 -> ccaO -> (free)
  float* S1 = S0 + S16;      // q -> x1
  float* S2 = S1 + S16;      // k -> qn -> lnf
  float* S3 = S2 + S16;      // v -> qh
  float* S4 = S3 + S16;      // saO -> x2
  float* W0 = S4 + S16;      // kvn(half) ; later ffn mid (spans W0+W1)
  float* W1 = W0 + W8;       // kh(half)
  float* W2 = W1 + W8;       // vh(half)

  dim3 blk(256);
  dim3 gProj(16, 64);  // N=1024, M=4096

  // ---- self attention ----
  ln_kernel<<<4096, blk, 0, stream>>>(x, sa_ln_g, sa_ln_b, S0);
  gemm_kernel<0><<<gProj, blk, 0, stream>>>(S0, sa_wq, nullptr, S1, 4096, 1024, 1024);
  gemm_kernel<0><<<gProj, blk, 0, stream>>>(S0, sa_wk, nullptr, S2, 4096, 1024, 1024);
  gemm_kernel<0><<<gProj, blk, 0, stream>>>(S0, sa_wv, nullptr, S3, 4096, 1024, 1024);
  attn_kernel<true><<<dim3(32, 16, 2), blk, 0, stream>>>(
      S1, S2, S3, S4, 2048, (size_t)2048 * 1024, (size_t)2048 * 1024);
  gemm_kernel<0><<<gProj, blk, 0, stream>>>(S4, sa_wo, x, S1, 4096, 1024, 1024);

  // ---- chunked cross attention ----
  ln_kernel<<<4096, blk, 0, stream>>>(S1, cca_lnq_g, cca_lnq_b, S2);
  gemm_kernel<0><<<gProj, blk, 0, stream>>>(S2, cca_wq, nullptr, S3, 4096, 1024, 1024);
  dim3 gHalf(16, 128);  // M=8192
  for (int half = 0; half < 2; ++half) {
    const float* nh = neigh + (size_t)half * 8192 * 1024;
    ln_kernel<<<8192, blk, 0, stream>>>(nh, cca_lnkv_g, cca_lnkv_b, W0);
    gemm_kernel<0><<<gHalf, blk, 0, stream>>>(W0, cca_wk, nullptr, W1, 8192, 1024, 1024);
    gemm_kernel<0><<<gHalf, blk, 0, stream>>>(W0, cca_wv, nullptr, W2, 8192, 1024, 1024);
    attn_kernel<false><<<dim3(1, 16, 32), blk, 0, stream>>>(
        S3 + (size_t)half * 32 * 64 * 1024, W1, W2,
        S0 + (size_t)half * 32 * 64 * 1024, 256, (size_t)64 * 1024,
        (size_t)256 * 1024);
  }
  gemm_kernel<0><<<gProj, blk, 0, stream>>>(S0, cca_wo, S1, S4, 4096, 1024, 1024);

  // ---- FFN ----
  ln_kernel<<<4096, blk, 0, stream>>>(S4, ffn_ln_g, ffn_ln_b, S2);
  gemm_kernel<1><<<dim3(64, 64), blk, 0, stream>>>(S2, ffn_w1, nullptr, W0, 4096, 4096, 1024);
  gemm_kernel<0><<<gProj, blk, 0, stream>>>(W0, ffn_w2, S4, out, 4096, 1024, 4096);
}

// Round 2
// 982.213 us; speedup vs baseline: 4.9474x; 4.9474x over previous
//
#include <hip/hip_runtime.h>
#include <math.h>

typedef __attribute__((ext_vector_type(8))) short bf16x8;
typedef __attribute__((ext_vector_type(4))) float f32x4;

#define MFMA(a, b, c) __builtin_amdgcn_mfma_f32_16x16x32_bf16((a), (b), (c), 0, 0, 0)

__device__ __forceinline__ unsigned short f2bf(float f) {
  union { float f; unsigned int u; } v; v.f = f;
  unsigned int r = v.u + 0x7fffu + ((v.u >> 16) & 1u);
  return (unsigned short)(r >> 16);
}

typedef __attribute__((address_space(1))) const void* as1cv;
typedef __attribute__((address_space(3))) void* as3v;
__device__ __forceinline__ void gl_lds16(const void* g, void* l) {
  __builtin_amdgcn_global_load_lds((as1cv)g, (as3v)l, 16, 0, 0);
}

// ---------------- LayerNorm fp32 -> bf16, one block per 1024-wide row -------
__global__ __launch_bounds__(256) void ln_bf16(
    const float* __restrict__ in, const float* __restrict__ gw,
    const float* __restrict__ bw, unsigned short* __restrict__ out) {
  int row = blockIdx.x;
  const float4* rp = (const float4*)(in + (size_t)row * 1024);
  float4 v = rp[threadIdx.x];
  float s = v.x + v.y + v.z + v.w;
  float ss = v.x * v.x + v.y * v.y + v.z * v.z + v.w * v.w;
#pragma unroll
  for (int o = 32; o; o >>= 1) {
    s += __shfl_down(s, o);
    ss += __shfl_down(ss, o);
  }
  __shared__ float red[10];
  int lane = threadIdx.x & 63, wid = threadIdx.x >> 6;
  if (lane == 0) { red[wid] = s; red[4 + wid] = ss; }
  __syncthreads();
  if (threadIdx.x == 0) {
    float ts = red[0] + red[1] + red[2] + red[3];
    float tss = red[4] + red[5] + red[6] + red[7];
    float mean = ts * (1.0f / 1024.0f);
    float var = tss * (1.0f / 1024.0f) - mean * mean;
    red[8] = mean;
    red[9] = rsqrtf(var + 1e-5f);
  }
  __syncthreads();
  float mean = red[8], rstd = red[9];
  float4 g = ((const float4*)gw)[threadIdx.x];
  float4 b = ((const float4*)bw)[threadIdx.x];
  ushort4 o;
  o.x = f2bf((v.x - mean) * rstd * g.x + b.x);
  o.y = f2bf((v.y - mean) * rstd * g.y + b.y);
  o.z = f2bf((v.z - mean) * rstd * g.z + b.z);
  o.w = f2bf((v.w - mean) * rstd * g.w + b.w);
  ((ushort4*)(out + (size_t)row * 1024))[threadIdx.x] = o;
}

// ---------------- weight fp32 [K][N] -> bf16 Wt [N][K] ----------------------
__global__ __launch_bounds__(256) void wtrans(
    const float* __restrict__ W, unsigned short* __restrict__ Wt, int K, int N) {
  __shared__ float Ts[32][33];
  int n0 = blockIdx.x * 32, k0 = blockIdx.y * 32;
  int ry = threadIdx.x >> 3, cx = (threadIdx.x & 7) * 4;
  float4 v = *(const float4*)(W + (size_t)(k0 + ry) * N + n0 + cx);
  Ts[ry][cx + 0] = v.x; Ts[ry][cx + 1] = v.y;
  Ts[ry][cx + 2] = v.z; Ts[ry][cx + 3] = v.w;
  __syncthreads();
  ushort4 o;
  o.x = f2bf(Ts[cx + 0][ry]); o.y = f2bf(Ts[cx + 1][ry]);
  o.z = f2bf(Ts[cx + 2][ry]); o.w = f2bf(Ts[cx + 3][ry]);
  *(ushort4*)(Wt + (size_t)(n0 + ry) * K + k0 + cx) = o;
}

// ---------------- bf16 MFMA GEMM: C = epi(A[M,K] @ Bt[N,K]^T) ---------------
// 128x128 tile, BK=32, 256 thr (4 waves 2x2), global_load_lds staging.
// EPI: 0 = bf16 out; 1 = fp32 out + fp32 residual; 2 = bf16 out with GELU;
//      3 = bf16 transposed-V out: Ct[(batch*16+h)*64+d][Tkv] (batch=row/Tkv).
template <int EPI>
__global__ __launch_bounds__(256) void gemm_bt(
    const unsigned short* __restrict__ A, const unsigned short* __restrict__ Bt,
    const float* __restrict__ R, void* __restrict__ Cv,
    int M, int N, int K, int rowOff, int Tkv) {
  __shared__ unsigned short As[128 * 32];
  __shared__ unsigned short Bs[128 * 32];
  const int tid = threadIdx.x;
  const int lane = tid & 63, w = tid >> 6;
  const int wr = w >> 1, wc = w & 1;
  const int lr = lane & 15, kb = lane >> 4;
  const int bn = blockIdx.x, bm = blockIdx.y;

  const int sRow = w * 16 + (lane >> 2);
  const int sCol = (lane & 3) * 8;
  const unsigned short* gA0 = A + (size_t)(bm * 128 + sRow) * K + sCol;
  const unsigned short* gA1 = gA0 + (size_t)64 * K;
  const unsigned short* gB0 = Bt + (size_t)(bn * 128 + sRow) * K + sCol;
  const unsigned short* gB1 = gB0 + (size_t)64 * K;
  unsigned short* lA0 = As + w * 512;
  unsigned short* lA1 = As + 2048 + w * 512;
  unsigned short* lB0 = Bs + w * 512;
  unsigned short* lB1 = Bs + 2048 + w * 512;

  const f32x4 z4 = {0.f, 0.f, 0.f, 0.f};
  f32x4 acc[4][4];
#pragma unroll
  for (int m = 0; m < 4; ++m)
#pragma unroll
    for (int n = 0; n < 4; ++n) acc[m][n] = z4;

  for (int k0 = 0; k0 < K; k0 += 32) {
    gl_lds16(gA0 + k0, lA0);
    gl_lds16(gA1 + k0, lA1);
    gl_lds16(gB0 + k0, lB0);
    gl_lds16(gB1 + k0, lB1);
    __syncthreads();
    bf16x8 aF[4], bF[4];
#pragma unroll
    for (int m = 0; m < 4; ++m)
      aF[m] = *(const bf16x8*)&As[(wr * 64 + m * 16 + lr) * 32 + kb * 8];
#pragma unroll
    for (int n = 0; n < 4; ++n)
      bF[n] = *(const bf16x8*)&Bs[(wc * 64 + n * 16 + lr) * 32 + kb * 8];
#pragma unroll
    for (int m = 0; m < 4; ++m)
#pragma unroll
      for (int n = 0; n < 4; ++n) acc[m][n] = MFMA(aF[m], bF[n], acc[m][n]);
    __syncthreads();
  }

#pragma unroll
  for (int m = 0; m < 4; ++m) {
    int row0 = bm * 128 + wr * 64 + m * 16 + kb * 4;
#pragma unroll
    for (int n = 0; n < 4; ++n) {
      int col = bn * 128 + wc * 64 + n * 16 + lr;
      f32x4 a = acc[m][n];
      if (EPI == 0 || EPI == 2) {
        unsigned short* C = (unsigned short*)Cv;
#pragma unroll
        for (int r = 0; r < 4; ++r) {
          float v = a[r];
          if (EPI == 2) v = 0.5f * v * (1.0f + erff(v * 0.70710678118654752f));
          C[(size_t)(row0 + r) * N + col] = f2bf(v);
        }
      } else if (EPI == 1) {
        float* C = (float*)Cv;
#pragma unroll
        for (int r = 0; r < 4; ++r)
          C[(size_t)(row0 + r) * N + col] =
              a.s0 * 0.0f + a[r] + R[(size_t)(row0 + r) * N + col];
      } else {
        unsigned short* C = (unsigned short*)Cv;
        int grow = rowOff + row0;
        int batch = grow / Tkv;
        int p = grow - batch * Tkv;
        int hh = col >> 6, d = col & 63;
        ushort4 st;
        st.x = f2bf(a[0]); st.y = f2bf(a[1]);
        st.z = f2bf(a[2]); st.w = f2bf(a[3]);
        *(ushort4*)&C[(((size_t)batch * 16 + hh) * 64 + d) * Tkv + p] = st;
      }
    }
  }
}

// ---------------- MFMA flash attention --------------------------------------
// Q,K merged bf16 [rows][1024]; Vt bf16 [(seq*16+h)*64+d][Tkv]; O bf16 merged.
// Block 256 thr = 4 waves; wave owns 16 q-rows; KV tiles of 64.
template <bool CAUSAL>
__global__ __launch_bounds__(256) void attn_mfma(
    const unsigned short* __restrict__ Q, const unsigned short* __restrict__ K,
    const unsigned short* __restrict__ Vt, unsigned short* __restrict__ O,
    int Tq, int Tkv) {
  __shared__ unsigned short Ps[4 * 16 * 64];  // per-wave 16x64 bf16, swizzled
  const int tid = threadIdx.x, lane = tid & 63, w = tid >> 6;
  const int lr = lane & 15, kb = lane >> 4;
  const int qt = blockIdx.x, h = blockIdx.y, z = blockIdx.z;

  const unsigned short* Qp =
      Q + ((size_t)z * Tq + qt * 64 + w * 16 + lr) * 1024 + h * 64;
  bf16x8 qf0 = *(const bf16x8*)(Qp + kb * 8);
  bf16x8 qf1 = *(const bf16x8*)(Qp + 32 + kb * 8);
  const unsigned short* Kb = K + (size_t)z * Tkv * 1024 + h * 64;
  const unsigned short* Vb = Vt + (size_t)(z * 16 + h) * 64 * Tkv;
  char* PsB = (char*)Ps + w * 2048;

  const f32x4 z4 = {0.f, 0.f, 0.f, 0.f};
  float m_[4] = {-INFINITY, -INFINITY, -INFINITY, -INFINITY};
  float l_[4] = {0.f, 0.f, 0.f, 0.f};
  f32x4 oacc[4];
#pragma unroll
  for (int n = 0; n < 4; ++n) oacc[n] = z4;

  const int ktMax = CAUSAL ? qt : (Tkv >> 6) - 1;
  for (int kt = 0; kt <= ktMax; ++kt) {
    f32x4 sac[4];
#pragma unroll
    for (int f = 0; f < 4; ++f) sac[f] = z4;
#pragma unroll
    for (int f = 0; f < 4; ++f) {
      const unsigned short* kp = Kb + (size_t)(kt * 64 + f * 16 + lr) * 1024;
      bf16x8 kf0 = *(const bf16x8*)(kp + kb * 8);
      bf16x8 kf1 = *(const bf16x8*)(kp + 32 + kb * 8);
      sac[f] = MFMA(qf0, kf0, sac[f]);
      sac[f] = MFMA(qf1, kf1, sac[f]);
    }
    float alpha[4], mn[4], rs[4];
#pragma unroll
    for (int r = 0; r < 4; ++r) {
      float t = -3e38f;
#pragma unroll
      for (int f = 0; f < 4; ++f) {
        float v = sac[f][r] * 0.125f;
        if (CAUSAL && kt == qt) {
          if (f * 16 + lr > w * 16 + kb * 4 + r) v = -3e38f;
        }
        sac[f][r] = v;
        t = fmaxf(t, v);
      }
      t = fmaxf(t, __shfl_xor(t, 1));
      t = fmaxf(t, __shfl_xor(t, 2));
      t = fmaxf(t, __shfl_xor(t, 4));
      t = fmaxf(t, __shfl_xor(t, 8));
      mn[r] = fmaxf(m_[r], t);
      alpha[r] = __expf(m_[r] - mn[r]);
      m_[r] = mn[r];
      rs[r] = 0.f;
    }
#pragma unroll
    for (int f = 0; f < 4; ++f) {
#pragma unroll
      for (int r = 0; r < 4; ++r) {
        float p = __expf(sac[f][r] - mn[r]);
        rs[r] += p;
        int q = kb * 4 + r, kv = f * 16 + lr;
        int byte = (q * 128 + kv * 2) ^ ((q & 7) << 4);
        *(unsigned short*)(PsB + byte) = f2bf(p);
      }
    }
#pragma unroll
    for (int r = 0; r < 4; ++r) {
      rs[r] += __shfl_xor(rs[r], 1);
      rs[r] += __shfl_xor(rs[r], 2);
      rs[r] += __shfl_xor(rs[r], 4);
      rs[r] += __shfl_xor(rs[r], 8);
      l_[r] = l_[r] * alpha[r] + rs[r];
    }
#pragma unroll
    for (int n = 0; n < 4; ++n) {
#pragma unroll
      for (int r = 0; r < 4; ++r) oacc[n][r] *= alpha[r];
    }
#pragma unroll
    for (int ks = 0; ks < 2; ++ks) {
      int byte = (lr * 128 + ks * 64 + kb * 16) ^ ((lr & 7) << 4);
      bf16x8 pf = *(const bf16x8*)(PsB + byte);
#pragma unroll
      for (int n = 0; n < 4; ++n) {
        const unsigned short* vp =
            Vb + (size_t)(n * 16 + lr) * Tkv + kt * 64 + ks * 32 + kb * 8;
        bf16x8 vf = *(const bf16x8*)vp;
        oacc[n] = MFMA(pf, vf, oacc[n]);
      }
    }
  }
  size_t orow0 = (size_t)z * Tq + qt * 64 + w * 16 + kb * 4;
#pragma unroll
  for (int r = 0; r < 4; ++r) {
    float inv = 1.0f / l_[r];
    unsigned short* op = O + (orow0 + r) * 1024 + h * 64;
#pragma unroll
    for (int n = 0; n < 4; ++n) op[n * 16 + lr] = f2bf(oacc[n][r] * inv);
  }
}

// ---------------- driver ----------------------------------------------------
extern "C" void kernel_launch(void* const* d_in, const int* in_sizes, int n_in,
                              void* d_out, int out_size, void* d_ws,
                              size_t ws_size, hipStream_t stream) {
  const float* x = (const float*)d_in[0];
  const float* neigh = (const float*)d_in[1];
  const float* sa_ln_g = (const float*)d_in[2];
  const float* sa_ln_b = (const float*)d_in[3];
  const float* sa_wq = (const float*)d_in[4];
  const float* sa_wk = (const float*)d_in[5];
  const float* sa_wv = (const float*)d_in[6];
  const float* sa_wo = (const float*)d_in[7];
  const float* cca_lnq_g = (const float*)d_in[8];
  const float* cca_lnq_b = (const float*)d_in[9];
  const float* cca_lnkv_g = (const float*)d_in[10];
  const float* cca_lnkv_b = (const float*)d_in[11];
  const float* cca_wq = (const float*)d_in[12];
  const float* cca_wk = (const float*)d_in[13];
  const float* cca_wv = (const float*)d_in[14];
  const float* cca_wo = (const float*)d_in[15];
  const float* ffn_ln_g = (const float*)d_in[16];
  const float* ffn_ln_b = (const float*)d_in[17];
  const float* ffn_w1 = (const float*)d_in[18];
  const float* ffn_w2 = (const float*)d_in[19];
  float* out = (float*)d_out;

  char* wsb = (char*)d_ws;
  const size_t MB = 1024 * 1024;
  unsigned short* wqT = (unsigned short*)(wsb + 0 * MB);
  unsigned short* wkT = (unsigned short*)(wsb + 2 * MB);
  unsigned short* wvT = (unsigned short*)(wsb + 4 * MB);
  unsigned short* woT = (unsigned short*)(wsb + 6 * MB);
  unsigned short* cwqT = (unsigned short*)(wsb + 8 * MB);
  unsigned short* cwkT = (unsigned short*)(wsb + 10 * MB);
  unsigned short* cwvT = (unsigned short*)(wsb + 12 * MB);
  unsigned short* cwoT = (unsigned short*)(wsb + 14 * MB);
  unsigned short* w1T = (unsigned short*)(wsb + 16 * MB);   // [4096][1024]
  unsigned short* w2T = (unsigned short*)(wsb + 24 * MB);   // [1024][4096]
  float* X1 = (float*)(wsb + 32 * MB);
  float* X2 = (float*)(wsb + 48 * MB);
  unsigned short* CKH = (unsigned short*)(wsb + 64 * MB);   // [16384][1024]; later FFN mid
  unsigned short* CVT = (unsigned short*)(wsb + 96 * MB);   // [64*16*64][256]
  unsigned short* A0 = (unsigned short*)(wsb + 128 * MB);
  unsigned short* QB = (unsigned short*)(wsb + 136 * MB);
  unsigned short* KB = (unsigned short*)(wsb + 144 * MB);
  unsigned short* VTs = (unsigned short*)(wsb + 152 * MB);  // [2*16*64][2048]
  unsigned short* AO = (unsigned short*)(wsb + 160 * MB);
  unsigned short* KVN = (unsigned short*)(wsb + 144 * MB);  // alias KB+VTs
  unsigned short* MID = CKH;                                // [4096][4096]

  dim3 blk(256);

  // weight conversion/transpose
  wtrans<<<dim3(32, 32), blk, 0, stream>>>(sa_wq, wqT, 1024, 1024);
  wtrans<<<dim3(32, 32), blk, 0, stream>>>(sa_wk, wkT, 1024, 1024);
  wtrans<<<dim3(32, 32), blk, 0, stream>>>(sa_wv, wvT, 1024, 1024);
  wtrans<<<dim3(32, 32), blk, 0, stream>>>(sa_wo, woT, 1024, 1024);
  wtrans<<<dim3(32, 32), blk, 0, stream>>>(cca_wq, cwqT, 1024, 1024);
  wtrans<<<dim3(32, 32), blk, 0, stream>>>(cca_wk, cwkT, 1024, 1024);
  wtrans<<<dim3(32, 32), blk, 0, stream>>>(cca_wv, cwvT, 1024, 1024);
  wtrans<<<dim3(32, 32), blk, 0, stream>>>(cca_wo, cwoT, 1024, 1024);
  wtrans<<<dim3(128, 32), blk, 0, stream>>>(ffn_w1, w1T, 1024, 4096);
  wtrans<<<dim3(32, 128), blk, 0, stream>>>(ffn_w2, w2T, 4096, 1024);

  // ---- self attention ----
  ln_bf16<<<4096, blk, 0, stream>>>(x, sa_ln_g, sa_ln_b, A0);
  gemm_bt<0><<<dim3(8, 32), blk, 0, stream>>>(A0, wqT, nullptr, QB, 4096, 1024, 1024, 0, 0);
  gemm_bt<0><<<dim3(8, 32), blk, 0, stream>>>(A0, wkT, nullptr, KB, 4096, 1024, 1024, 0, 0);
  gemm_bt<3><<<dim3(8, 32), blk, 0, stream>>>(A0, wvT, nullptr, VTs, 4096, 1024, 1024, 0, 2048);
  attn_mfma<true><<<dim3(32, 16, 2), blk, 0, stream>>>(QB, KB, VTs, AO, 2048, 2048);
  gemm_bt<1><<<dim3(8, 32), blk, 0, stream>>>(AO, woT, x, X1, 4096, 1024, 1024, 0, 0);

  // ---- chunked cross attention ----
  ln_bf16<<<4096, blk, 0, stream>>>(X1, cca_lnq_g, cca_lnq_b, A0);
  gemm_bt<0><<<dim3(8, 32), blk, 0, stream>>>(A0, cwqT, nullptr, QB, 4096, 1024, 1024, 0, 0);
  for (int half = 0; half < 2; ++half) {
    const float* nh = neigh + (size_t)half * 8192 * 1024;
    ln_bf16<<<8192, blk, 0, stream>>>(nh, cca_lnkv_g, cca_lnkv_b, KVN);
    gemm_bt<0><<<dim3(8, 64), blk, 0, stream>>>(
        KVN, cwkT, nullptr, CKH + (size_t)half * 8192 * 1024, 8192, 1024, 1024, 0, 0);
    gemm_bt<3><<<dim3(8, 64), blk, 0, stream>>>(
        KVN, cwvT, nullptr, CVT, 8192, 1024, 1024, half * 8192, 256);
  }
  attn_mfma<false><<<dim3(1, 16, 64), blk, 0, stream>>>(QB, CKH, CVT, AO, 64, 256);
  gemm_bt<1><<<dim3(8, 32), blk, 0, stream>>>(AO, cwoT, X1, X2, 4096, 1024, 1024, 0, 0);

  // ---- FFN ----
  ln_bf16<<<4096, blk, 0, stream>>>(X2, ffn_ln_g, ffn_ln_b, A0);
  gemm_bt<2><<<dim3(32, 32), blk, 0, stream>>>(A0, w1T, nullptr, MID, 4096, 4096, 1024, 0, 0);
  gemm_bt<1><<<dim3(8, 32), blk, 0, stream>>>(MID, w2T, X2, out, 4096, 1024, 4096, 0, 0);
}

// Round 3
// 954.354 us; speedup vs baseline: 5.0919x; 1.0292x over previous
//
#include <hip/hip_runtime.h>
#include <math.h>

typedef __attribute__((ext_vector_type(8))) short bf16x8;
typedef __attribute__((ext_vector_type(4))) float f32x4;

#define MFMA(a, b, c) __builtin_amdgcn_mfma_f32_16x16x32_bf16((a), (b), (c), 0, 0, 0)

__device__ __forceinline__ unsigned short f2bf(float f) {
  union { float f; unsigned int u; } v; v.f = f;
  unsigned int r = v.u + 0x7fffu + ((v.u >> 16) & 1u);
  return (unsigned short)(r >> 16);
}
__device__ __forceinline__ float bf2f(unsigned short u) {
  union { unsigned int u; float f; } v; v.u = ((unsigned int)u) << 16;
  return v.f;
}

typedef __attribute__((address_space(1))) const void* as1cv;
typedef __attribute__((address_space(3))) void* as3v;
__device__ __forceinline__ void gl_lds16(const void* g, void* l) {
  __builtin_amdgcn_global_load_lds((as1cv)g, (as3v)l, 16, 0, 0);
}

// ---------------- LayerNorm fp32 -> bf16, one block per 1024-wide row -------
__global__ __launch_bounds__(256) void ln_bf16(
    const float* __restrict__ in, const float* __restrict__ gw,
    const float* __restrict__ bw, unsigned short* __restrict__ out) {
  int row = blockIdx.x;
  const float4* rp = (const float4*)(in + (size_t)row * 1024);
  float4 v = rp[threadIdx.x];
  float s = v.x + v.y + v.z + v.w;
  float ss = v.x * v.x + v.y * v.y + v.z * v.z + v.w * v.w;
#pragma unroll
  for (int o = 32; o; o >>= 1) {
    s += __shfl_down(s, o);
    ss += __shfl_down(ss, o);
  }
  __shared__ float red[10];
  int lane = threadIdx.x & 63, wid = threadIdx.x >> 6;
  if (lane == 0) { red[wid] = s; red[4 + wid] = ss; }
  __syncthreads();
  if (threadIdx.x == 0) {
    float ts = red[0] + red[1] + red[2] + red[3];
    float tss = red[4] + red[5] + red[6] + red[7];
    float mean = ts * (1.0f / 1024.0f);
    float var = tss * (1.0f / 1024.0f) - mean * mean;
    red[8] = mean;
    red[9] = rsqrtf(var + 1e-5f);
  }
  __syncthreads();
  float mean = red[8], rstd = red[9];
  float4 g = ((const float4*)gw)[threadIdx.x];
  float4 b = ((const float4*)bw)[threadIdx.x];
  ushort4 o;
  o.x = f2bf((v.x - mean) * rstd * g.x + b.x);
  o.y = f2bf((v.y - mean) * rstd * g.y + b.y);
  o.z = f2bf((v.z - mean) * rstd * g.z + b.z);
  o.w = f2bf((v.w - mean) * rstd * g.w + b.w);
  ((ushort4*)(out + (size_t)row * 1024))[threadIdx.x] = o;
}

// ---------------- weight fp32 [K][N] -> bf16 Wt [N][K] ----------------------
__global__ __launch_bounds__(256) void wtrans(
    const float* __restrict__ W, unsigned short* __restrict__ Wt, int K, int N) {
  __shared__ float Ts[32][33];
  int n0 = blockIdx.x * 32, k0 = blockIdx.y * 32;
  int ry = threadIdx.x >> 3, cx = (threadIdx.x & 7) * 4;
  float4 v = *(const float4*)(W + (size_t)(k0 + ry) * N + n0 + cx);
  Ts[ry][cx + 0] = v.x; Ts[ry][cx + 1] = v.y;
  Ts[ry][cx + 2] = v.z; Ts[ry][cx + 3] = v.w;
  __syncthreads();
  ushort4 o;
  o.x = f2bf(Ts[cx + 0][ry]); o.y = f2bf(Ts[cx + 1][ry]);
  o.z = f2bf(Ts[cx + 2][ry]); o.w = f2bf(Ts[cx + 3][ry]);
  *(ushort4*)(Wt + (size_t)(n0 + ry) * K + k0 + cx) = o;
}

// ---------------- bf16 MFMA GEMM: C = epi(A[M,K] @ Bt[N,K]^T) ---------------
// 128x128 tile, BK=32, 256 thr (4 waves 2x2), global_load_lds staging.
// EPI: 0 = bf16 out; 1 = fp32 out + fp32 residual; 2 = bf16 out with GELU;
//      4 = split epilogue: col<vSplit -> plain bf16 into segment (col>>10)
//          (each segment is [M][1024] at Cv + seg*M*1024); col>=vSplit ->
//          transposed-V: Vb[((row/Tkv)*16+h)*64+d][Tkv] at seg vSplit>>10.
template <int EPI>
__global__ __launch_bounds__(256) void gemm_bt(
    const unsigned short* __restrict__ A, const unsigned short* __restrict__ Bt,
    const float* __restrict__ R, void* __restrict__ Cv,
    int M, int N, int K, int vSplit, int Tkv) {
  __shared__ unsigned short As[128 * 32];
  __shared__ unsigned short Bs[128 * 32];
  const int tid = threadIdx.x;
  const int lane = tid & 63, w = tid >> 6;
  const int wr = w >> 1, wc = w & 1;
  const int lr = lane & 15, kb = lane >> 4;
  const int bn = blockIdx.x, bm = blockIdx.y;

  const int sRow = w * 16 + (lane >> 2);
  const int sCol = (lane & 3) * 8;
  const unsigned short* gA0 = A + (size_t)(bm * 128 + sRow) * K + sCol;
  const unsigned short* gA1 = gA0 + (size_t)64 * K;
  const unsigned short* gB0 = Bt + (size_t)(bn * 128 + sRow) * K + sCol;
  const unsigned short* gB1 = gB0 + (size_t)64 * K;
  unsigned short* lA0 = As + w * 512;
  unsigned short* lA1 = As + 2048 + w * 512;
  unsigned short* lB0 = Bs + w * 512;
  unsigned short* lB1 = Bs + 2048 + w * 512;

  const f32x4 z4 = {0.f, 0.f, 0.f, 0.f};
  f32x4 acc[4][4];
#pragma unroll
  for (int m = 0; m < 4; ++m)
#pragma unroll
    for (int n = 0; n < 4; ++n) acc[m][n] = z4;

  for (int k0 = 0; k0 < K; k0 += 32) {
    gl_lds16(gA0 + k0, lA0);
    gl_lds16(gA1 + k0, lA1);
    gl_lds16(gB0 + k0, lB0);
    gl_lds16(gB1 + k0, lB1);
    __syncthreads();
    bf16x8 aF[4], bF[4];
#pragma unroll
    for (int m = 0; m < 4; ++m)
      aF[m] = *(const bf16x8*)&As[(wr * 64 + m * 16 + lr) * 32 + kb * 8];
#pragma unroll
    for (int n = 0; n < 4; ++n)
      bF[n] = *(const bf16x8*)&Bs[(wc * 64 + n * 16 + lr) * 32 + kb * 8];
#pragma unroll
    for (int m = 0; m < 4; ++m)
#pragma unroll
      for (int n = 0; n < 4; ++n) acc[m][n] = MFMA(aF[m], bF[n], acc[m][n]);
    __syncthreads();
  }

#pragma unroll
  for (int m = 0; m < 4; ++m) {
    int row0 = bm * 128 + wr * 64 + m * 16 + kb * 4;
#pragma unroll
    for (int n = 0; n < 4; ++n) {
      int col = bn * 128 + wc * 64 + n * 16 + lr;
      f32x4 a = acc[m][n];
      if (EPI == 0 || EPI == 2) {
        unsigned short* C = (unsigned short*)Cv;
#pragma unroll
        for (int r = 0; r < 4; ++r) {
          float v = a[r];
          if (EPI == 2) v = 0.5f * v * (1.0f + erff(v * 0.70710678118654752f));
          C[(size_t)(row0 + r) * N + col] = f2bf(v);
        }
      } else if (EPI == 1) {
        float* C = (float*)Cv;
#pragma unroll
        for (int r = 0; r < 4; ++r)
          C[(size_t)(row0 + r) * N + col] =
              a[r] + R[(size_t)(row0 + r) * N + col];
      } else {  // EPI 4
        if (col < vSplit) {
          unsigned short* C =
              (unsigned short*)Cv + (size_t)(col >> 10) * ((size_t)M << 10);
          int cl = col & 1023;
#pragma unroll
          for (int r = 0; r < 4; ++r)
            C[(size_t)(row0 + r) * 1024 + cl] = f2bf(a[r]);
        } else {
          unsigned short* Vb =
              (unsigned short*)Cv + (size_t)(vSplit >> 10) * ((size_t)M << 10);
          int cv = col - vSplit;
          int hh = cv >> 6, d = cv & 63;
          int batch = row0 / Tkv;
          int p = row0 - batch * Tkv;
          ushort4 st;
          st.x = f2bf(a[0]); st.y = f2bf(a[1]);
          st.z = f2bf(a[2]); st.w = f2bf(a[3]);
          *(ushort4*)&Vb[(((size_t)batch * 16 + hh) * 64 + d) * Tkv + p] = st;
        }
      }
    }
  }
}

// ---------------- MFMA flash attention with K/V register prefetch ----------
// Q,K merged bf16 [rows][1024]; Vt bf16 [(seq*16+h)*64+d][Tkv]; O bf16 merged.
// 256 thr = 4 waves; wave owns 16 q-rows; KV tiles of 64; Q pre-scaled 1/8.
template <bool CAUSAL>
__global__ __launch_bounds__(256, 4) void attn_mfma(
    const unsigned short* __restrict__ Q, const unsigned short* __restrict__ K,
    const unsigned short* __restrict__ Vt, unsigned short* __restrict__ O,
    int Tq, int Tkv) {
  __shared__ unsigned short Ps[4 * 16 * 64];  // per-wave 16x64 bf16, swizzled
  const int tid = threadIdx.x, lane = tid & 63, w = tid >> 6;
  const int lr = lane & 15, kb = lane >> 4;
  int qt = blockIdx.x;
  if (CAUSAL) qt = (blockIdx.x + blockIdx.y) & 31;  // scramble: CU work balance
  const int h = blockIdx.y, z = blockIdx.z;

  const unsigned short* Qp =
      Q + ((size_t)z * Tq + qt * 64 + w * 16 + lr) * 1024 + h * 64;
  bf16x8 qf0 = *(const bf16x8*)(Qp + kb * 8);
  bf16x8 qf1 = *(const bf16x8*)(Qp + 32 + kb * 8);
  // fold softmax scale 1/8 into Q (exact: power of two)
#pragma unroll
  for (int j = 0; j < 8; ++j) {
    qf0[j] = (short)f2bf(bf2f((unsigned short)qf0[j]) * 0.125f);
    qf1[j] = (short)f2bf(bf2f((unsigned short)qf1[j]) * 0.125f);
  }
  const unsigned short* Kb = K + (size_t)z * Tkv * 1024 + h * 64;
  const unsigned short* Vb = Vt + (size_t)(z * 16 + h) * 64 * Tkv;
  char* PsB = (char*)Ps + w * 2048;

  const f32x4 z4 = {0.f, 0.f, 0.f, 0.f};
  float m_[4] = {-INFINITY, -INFINITY, -INFINITY, -INFINITY};
  float l_[4] = {0.f, 0.f, 0.f, 0.f};
  f32x4 oacc[4];
#pragma unroll
  for (int n = 0; n < 4; ++n) oacc[n] = z4;

  const int ktMax = CAUSAL ? qt : (Tkv >> 6) - 1;

  bf16x8 kf[8];
  auto kload = [&](int kt) {
#pragma unroll
    for (int f = 0; f < 4; ++f) {
      const unsigned short* kp = Kb + (size_t)(kt * 64 + f * 16 + lr) * 1024;
      kf[f * 2 + 0] = *(const bf16x8*)(kp + kb * 8);
      kf[f * 2 + 1] = *(const bf16x8*)(kp + 32 + kb * 8);
    }
  };
  kload(0);

  for (int kt = 0; kt <= ktMax; ++kt) {
    // prefetch V tile now; consumed after softmax (~400cy later)
    bf16x8 vf[8];
#pragma unroll
    for (int ks = 0; ks < 2; ++ks)
#pragma unroll
      for (int n = 0; n < 4; ++n)
        vf[ks * 4 + n] = *(const bf16x8*)(Vb + (size_t)(n * 16 + lr) * Tkv +
                                          kt * 64 + ks * 32 + kb * 8);
    f32x4 sac[4];
#pragma unroll
    for (int f = 0; f < 4; ++f) sac[f] = z4;
#pragma unroll
    for (int f = 0; f < 4; ++f) {
      sac[f] = MFMA(qf0, kf[f * 2 + 0], sac[f]);
      sac[f] = MFMA(qf1, kf[f * 2 + 1], sac[f]);
    }
    if (kt < ktMax) kload(kt + 1);  // prefetch next K under softmax+PV

    float alpha[4], mn[4], rs[4];
#pragma unroll
    for (int r = 0; r < 4; ++r) {
      float t = -3e38f;
#pragma unroll
      for (int f = 0; f < 4; ++f) {
        float v = sac[f][r];
        if (CAUSAL && kt == qt) {
          if (f * 16 + lr > w * 16 + kb * 4 + r) v = -3e38f;
        }
        sac[f][r] = v;
        t = fmaxf(t, v);
      }
      t = fmaxf(t, __shfl_xor(t, 1));
      t = fmaxf(t, __shfl_xor(t, 2));
      t = fmaxf(t, __shfl_xor(t, 4));
      t = fmaxf(t, __shfl_xor(t, 8));
      mn[r] = fmaxf(m_[r], t);
      alpha[r] = __expf(m_[r] - mn[r]);
      m_[r] = mn[r];
      rs[r] = 0.f;
    }
#pragma unroll
    for (int f = 0; f < 4; ++f) {
#pragma unroll
      for (int r = 0; r < 4; ++r) {
        float p = __expf(sac[f][r] - mn[r]);
        rs[r] += p;
        int q = kb * 4 + r, kv = f * 16 + lr;
        int byte = (q * 128 + kv * 2) ^ ((q & 7) << 4);
        *(unsigned short*)(PsB + byte) = f2bf(p);
      }
    }
#pragma unroll
    for (int r = 0; r < 4; ++r) {
      rs[r] += __shfl_xor(rs[r], 1);
      rs[r] += __shfl_xor(rs[r], 2);
      rs[r] += __shfl_xor(rs[r], 4);
      rs[r] += __shfl_xor(rs[r], 8);
      l_[r] = l_[r] * alpha[r] + rs[r];
    }
#pragma unroll
    for (int n = 0; n < 4; ++n) {
#pragma unroll
      for (int r = 0; r < 4; ++r) oacc[n][r] *= alpha[r];
    }
#pragma unroll
    for (int ks = 0; ks < 2; ++ks) {
      int byte = (lr * 128 + ks * 64 + kb * 16) ^ ((lr & 7) << 4);
      bf16x8 pf = *(const bf16x8*)(PsB + byte);
#pragma unroll
      for (int n = 0; n < 4; ++n) oacc[n] = MFMA(pf, vf[ks * 4 + n], oacc[n]);
    }
  }
  size_t orow0 = (size_t)z * Tq + qt * 64 + w * 16 + kb * 4;
#pragma unroll
  for (int r = 0; r < 4; ++r) {
    float inv = 1.0f / l_[r];
    unsigned short* op = O + (orow0 + r) * 1024 + h * 64;
#pragma unroll
    for (int n = 0; n < 4; ++n) op[n * 16 + lr] = f2bf(oacc[n][r] * inv);
  }
}

// ---------------- driver ----------------------------------------------------
extern "C" void kernel_launch(void* const* d_in, const int* in_sizes, int n_in,
                              void* d_out, int out_size, void* d_ws,
                              size_t ws_size, hipStream_t stream) {
  const float* x = (const float*)d_in[0];
  const float* neigh = (const float*)d_in[1];
  const float* sa_ln_g = (const float*)d_in[2];
  const float* sa_ln_b = (const float*)d_in[3];
  const float* sa_wq = (const float*)d_in[4];
  const float* sa_wk = (const float*)d_in[5];
  const float* sa_wv = (const float*)d_in[6];
  const float* sa_wo = (const float*)d_in[7];
  const float* cca_lnq_g = (const float*)d_in[8];
  const float* cca_lnq_b = (const float*)d_in[9];
  const float* cca_lnkv_g = (const float*)d_in[10];
  const float* cca_lnkv_b = (const float*)d_in[11];
  const float* cca_wq = (const float*)d_in[12];
  const float* cca_wk = (const float*)d_in[13];
  const float* cca_wv = (const float*)d_in[14];
  const float* cca_wo = (const float*)d_in[15];
  const float* ffn_ln_g = (const float*)d_in[16];
  const float* ffn_ln_b = (const float*)d_in[17];
  const float* ffn_w1 = (const float*)d_in[18];
  const float* ffn_w2 = (const float*)d_in[19];
  float* out = (float*)d_out;

  char* wsb = (char*)d_ws;
  const size_t MB = 1024 * 1024;
  unsigned short* wqkvT = (unsigned short*)(wsb + 0 * MB);   // [3072][1024]
  unsigned short* woT = (unsigned short*)(wsb + 6 * MB);     // [1024][1024]
  unsigned short* cwqT = (unsigned short*)(wsb + 8 * MB);
  unsigned short* cwkvT = (unsigned short*)(wsb + 10 * MB);  // [2048][1024]
  unsigned short* cwoT = (unsigned short*)(wsb + 14 * MB);
  unsigned short* w1T = (unsigned short*)(wsb + 16 * MB);    // [4096][1024]
  unsigned short* w2T = (unsigned short*)(wsb + 24 * MB);    // [1024][4096]
  float* X1 = (float*)(wsb + 32 * MB);
  float* X2 = (float*)(wsb + 48 * MB);
  unsigned short* CKH = (unsigned short*)(wsb + 64 * MB);    // [16384][1024]
  unsigned short* CVT = (unsigned short*)(wsb + 96 * MB);    // [64*16*64][256]
  unsigned short* A0 = (unsigned short*)(wsb + 128 * MB);    // [4096][1024]
  unsigned short* QB = (unsigned short*)(wsb + 136 * MB);    // [4096][1024]
  unsigned short* KB = (unsigned short*)(wsb + 144 * MB);    // [4096][1024]
  unsigned short* VTs = (unsigned short*)(wsb + 152 * MB);   // [2*16*64][2048]
  unsigned short* KVN = (unsigned short*)(wsb + 144 * MB);   // [16384][1024] (after SA)
  unsigned short* AO = (unsigned short*)(wsb + 168 * MB);    // [4096][1024]
  unsigned short* MID = CKH;                                 // [4096][4096]

  dim3 blk(256);

  // weight conversion/transpose (QKV packed rows 0/1024/2048; CCA KV packed)
  wtrans<<<dim3(32, 32), blk, 0, stream>>>(sa_wq, wqkvT, 1024, 1024);
  wtrans<<<dim3(32, 32), blk, 0, stream>>>(sa_wk, wqkvT + 1024 * 1024, 1024, 1024);
  wtrans<<<dim3(32, 32), blk, 0, stream>>>(sa_wv, wqkvT + 2 * 1024 * 1024, 1024, 1024);
  wtrans<<<dim3(32, 32), blk, 0, stream>>>(sa_wo, woT, 1024, 1024);
  wtrans<<<dim3(32, 32), blk, 0, stream>>>(cca_wq, cwqT, 1024, 1024);
  wtrans<<<dim3(32, 32), blk, 0, stream>>>(cca_wk, cwkvT, 1024, 1024);
  wtrans<<<dim3(32, 32), blk, 0, stream>>>(cca_wv, cwkvT + 1024 * 1024, 1024, 1024);
  wtrans<<<dim3(32, 32), blk, 0, stream>>>(cca_wo, cwoT, 1024, 1024);
  wtrans<<<dim3(128, 32), blk, 0, stream>>>(ffn_w1, w1T, 1024, 4096);
  wtrans<<<dim3(32, 128), blk, 0, stream>>>(ffn_w2, w2T, 4096, 1024);

  // ---- self attention ----
  ln_bf16<<<4096, blk, 0, stream>>>(x, sa_ln_g, sa_ln_b, A0);
  // fused QKV: N=3072; Q->QB, K->KB, V->VTs (transposed, Tkv=2048)
  gemm_bt<4><<<dim3(24, 32), blk, 0, stream>>>(A0, wqkvT, nullptr, QB, 4096,
                                               3072, 1024, 2048, 2048);
  attn_mfma<true><<<dim3(32, 16, 2), blk, 0, stream>>>(QB, KB, VTs, AO, 2048, 2048);
  gemm_bt<1><<<dim3(8, 32), blk, 0, stream>>>(AO, woT, x, X1, 4096, 1024, 1024, 0, 0);

  // ---- chunked cross attention ----
  ln_bf16<<<4096, blk, 0, stream>>>(X1, cca_lnq_g, cca_lnq_b, A0);
  gemm_bt<0><<<dim3(8, 32), blk, 0, stream>>>(A0, cwqT, nullptr, QB, 4096, 1024, 1024, 0, 0);
  ln_bf16<<<16384, blk, 0, stream>>>(neigh, cca_lnkv_g, cca_lnkv_b, KVN);
  // fused KV: N=2048; K->CKH, V->CVT (transposed, Tkv=256)
  gemm_bt<4><<<dim3(16, 128), blk, 0, stream>>>(KVN, cwkvT, nullptr, CKH, 16384,
                                                2048, 1024, 1024, 256);
  attn_mfma<false><<<dim3(1, 16, 64), blk, 0, stream>>>(QB, CKH, CVT, AO, 64, 256);
  gemm_bt<1><<<dim3(8, 32), blk, 0, stream>>>(AO, cwoT, X1, X2, 4096, 1024, 1024, 0, 0);

  // ---- FFN ----
  ln_bf16<<<4096, blk, 0, stream>>>(X2, ffn_ln_g, ffn_ln_b, A0);
  gemm_bt<2><<<dim3(32, 32), blk, 0, stream>>>(A0, w1T, nullptr, MID, 4096, 4096, 1024, 0, 0);
  gemm_bt<1><<<dim3(8, 32), blk, 0, stream>>>(MID, w2T, X2, out, 4096, 1024, 4096, 0, 0);
}